// Round 2
// baseline (216.078 us; speedup 1.0000x reference)
//
#include <hip/hip_runtime.h>
#include <hip/hip_bf16.h>

typedef __bf16 bf16x8 __attribute__((ext_vector_type(8)));
typedef __bf16 bf16x4 __attribute__((ext_vector_type(4)));
typedef float  f32x4  __attribute__((ext_vector_type(4)));

constexpr int BATCH = 2, H = 8, NQ = 1024, SEQ = 8192, DIM = 256, HD = 32;
constexpr float SCALE = 0.17677669529663687f;   // 32^-0.5
constexpr float LOG2E = 1.4426950408889634f;
constexpr float QSCALE = SCALE * LOG2E;         // fold log2(e): softmax in exp2 domain
constexpr float MASKC = 100.0f * LOG2E;

// workspace layout (bytes)
constexpr size_t OFF_QH  = 0;                                      // bf16 [B*H][NQ][32]
constexpr size_t OFF_KH  = OFF_QH  + (size_t)BATCH*H*NQ*HD*2;      // bf16 [B*H][S][32]
constexpr size_t OFF_VT  = OFF_KH  + (size_t)BATCH*H*SEQ*HD*2;     // bf16 [B*H][32][S]
constexpr size_t OFF_CTX = OFF_VT  + (size_t)BATCH*H*SEQ*HD*2;     // f32  [B*NQ][256]
constexpr size_t OFF_W   = OFF_CTX + (size_t)BATCH*NQ*DIM*4;       // bf16 4 x [256][256]

__global__ void prep_weights_kernel(const float* __restrict__ Wq, const float* __restrict__ Wk,
                                    const float* __restrict__ Wv, const float* __restrict__ Wo,
                                    __bf16* __restrict__ out) {
    int i = blockIdx.x * 256 + threadIdx.x;          // 65536 threads
    out[i]          = (__bf16)(Wq[i] * QSCALE);      // fold q-scale * log2e into Wq
    out[65536 + i]  = (__bf16)(Wk[i]);
    out[131072 + i] = (__bf16)(Wv[i]);
    out[196608 + i] = (__bf16)(Wo[i]);
}

// Y = bf16(X[M x 256]) @ Wbf^T + bias.  Block: 64 rows x all 256 cols, 4 waves.
// MODE 0: bf16 head layout [b*H+h][row][hd]   (Q and K)
// MODE 1: bf16 transposed  [b*H+h][hd][row]   (V^T; MFMA operands swapped)
// MODE 2: f32 plain [m][n]                    (final output)
template<int MODE>
__global__ __launch_bounds__(256, 2)
void proj_kernel(const float* __restrict__ X, const __bf16* __restrict__ W,
                 const float* __restrict__ bias, float bias_scale,
                 void* __restrict__ outp, int Mb)
{
    __shared__ __bf16 Ash[64][40];    // 64 rows x 32 k (+8 pad)
    __shared__ __bf16 Bsh[256][40];   // 256 n  x 32 k (+8 pad)
    const int m0 = blockIdx.x * 64;
    const int t = threadIdx.x;
    const int w = t >> 6;
    const int lane = t & 63;
    const int g = lane >> 4;
    const int lr = lane & 15;

    f32x4 acc[4][4] = {};

    for (int kk = 0; kk < DIM; kk += 32) {
        __syncthreads();
        #pragma unroll
        for (int i = 0; i < 2; ++i) {
            int c = t * 2 + i;
            int row = c >> 3;
            int q = c & 7;
            const float4 v = *reinterpret_cast<const float4*>(X + (size_t)(m0 + row) * DIM + kk + q * 4);
            bf16x4 bv;
            bv[0] = (__bf16)v.x; bv[1] = (__bf16)v.y; bv[2] = (__bf16)v.z; bv[3] = (__bf16)v.w;
            *reinterpret_cast<bf16x4*>(&Ash[row][q * 4]) = bv;
        }
        #pragma unroll
        for (int i = 0; i < 4; ++i) {
            int c = t * 4 + i;
            int n = c >> 2;
            int q = c & 3;
            *reinterpret_cast<bf16x8*>(&Bsh[n][q * 8]) =
                *reinterpret_cast<const bf16x8*>(W + (size_t)n * DIM + kk + q * 8);
        }
        __syncthreads();

        bf16x8 af[4], bfr[4];
        #pragma unroll
        for (int mt = 0; mt < 4; ++mt)
            af[mt] = *reinterpret_cast<const bf16x8*>(&Ash[mt * 16 + lr][g * 8]);
        #pragma unroll
        for (int nt = 0; nt < 4; ++nt)
            bfr[nt] = *reinterpret_cast<const bf16x8*>(&Bsh[w * 64 + nt * 16 + lr][g * 8]);
        #pragma unroll
        for (int mt = 0; mt < 4; ++mt)
            #pragma unroll
            for (int nt = 0; nt < 4; ++nt) {
                if (MODE == 1)
                    acc[mt][nt] = __builtin_amdgcn_mfma_f32_16x16x32_bf16(bfr[nt], af[mt], acc[mt][nt], 0, 0, 0);
                else
                    acc[mt][nt] = __builtin_amdgcn_mfma_f32_16x16x32_bf16(af[mt], bfr[nt], acc[mt][nt], 0, 0, 0);
            }
    }

    const int bb = m0 / Mb;            // whole block lies in one batch (64 | Mb)
    const int sbase = m0 - bb * Mb;

    if (MODE == 0) {
        __bf16* outb = (__bf16*)outp;
        #pragma unroll
        for (int nt = 0; nt < 4; ++nt) {
            int n = w * 64 + nt * 16 + lr;
            float bv = bias[n] * bias_scale;
            int h = n >> 5, hd = n & 31;
            __bf16* op = outb + ((size_t)(bb * H + h) * Mb) * 32 + hd;
            #pragma unroll
            for (int mt = 0; mt < 4; ++mt)
                #pragma unroll
                for (int r = 0; r < 4; ++r) {
                    int s = sbase + mt * 16 + g * 4 + r;
                    op[(size_t)s * 32] = (__bf16)(acc[mt][nt][r] + bv);
                }
        }
    } else if (MODE == 1) {
        __bf16* outb = (__bf16*)outp;
        #pragma unroll
        for (int nt = 0; nt < 4; ++nt)
            #pragma unroll
            for (int r = 0; r < 4; ++r) {
                int n = w * 64 + nt * 16 + g * 4 + r;   // D rows = n (operands swapped)
                float bv = bias[n] * bias_scale;
                int h = n >> 5, hd = n & 31;
                __bf16* op = outb + ((size_t)(bb * H + h) * 32 + hd) * SEQ;
                #pragma unroll
                for (int mt = 0; mt < 4; ++mt) {
                    int s = sbase + mt * 16 + lr;       // D cols = m (contiguous per 16 lanes)
                    op[s] = (__bf16)(acc[mt][nt][r] + bv);
                }
            }
    } else {
        float* outf = (float*)outp;
        #pragma unroll
        for (int nt = 0; nt < 4; ++nt) {
            int n = w * 64 + nt * 16 + lr;
            float bv = bias[n] * bias_scale;
            #pragma unroll
            for (int mt = 0; mt < 4; ++mt)
                #pragma unroll
                for (int r = 0; r < 4; ++r) {
                    int m = m0 + mt * 16 + g * 4 + r;
                    outf[(size_t)m * DIM + n] = acc[mt][nt][r] + bv;
                }
        }
    }
}

// Flash attention, flash-decoding style in-block S-split.
// Grid 1024 = 16 (bh, low bits -> XCD locality) x 64 q-tiles of 16 rows.
// Block = 4 waves; wave w handles kv chunk [w*2048, (w+1)*2048) with online softmax
// (exp2 domain); partials merged via LDS.
// Swapped QK^T: S^T = mfma(K_frag, Q_frag): lane owns q-row (lane&15), kpos = g*4+reg (+16).
__global__ __launch_bounds__(256, 4)
void attn_kernel(const __bf16* __restrict__ qh, const __bf16* __restrict__ kh,
                 const __bf16* __restrict__ vt, const float* __restrict__ mask,
                 float* __restrict__ ctx)
{
    __shared__ float part[4][64][10];
    const int bid = blockIdx.x;
    const int bh = bid & 15;
    const int qt = bid >> 4;              // 0..63
    const int b = bh >> 3, h = bh & 7;
    const int t = threadIdx.x;
    const int w = t >> 6, lane = t & 63, g = lane >> 4, lr = lane & 15;
    const int q0 = qt * 16;

    const bf16x8 qf = *reinterpret_cast<const bf16x8*>(qh + ((size_t)bh * NQ + q0 + lr) * HD + g * 8);
    const __bf16* kb = kh + (size_t)bh * SEQ * HD;
    const __bf16* vrow0 = vt + ((size_t)bh * HD + lr) * SEQ;
    const __bf16* vrow1 = vrow0 + (size_t)16 * SEQ;
    const float* mb = mask + (size_t)b * SEQ;

    const int kv0 = w * (SEQ / 4);
    const int kvend = kv0 + SEQ / 4;

    float m_run = -3.0e38f, l_run = 0.f;
    f32x4 o0 = {0.f, 0.f, 0.f, 0.f}, o1 = {0.f, 0.f, 0.f, 0.f};
    const f32x4 zero = {0.f, 0.f, 0.f, 0.f};

    for (int kv = kv0; kv < kvend; kv += 64) {
        f32x4 s[4];
        #pragma unroll
        for (int j = 0; j < 4; ++j) {
            bf16x8 kf = *reinterpret_cast<const bf16x8*>(kb + (size_t)(kv + j * 16 + lr) * HD + g * 8);
            s[j] = __builtin_amdgcn_mfma_f32_16x16x32_bf16(kf, qf, zero, 0, 0, 0);
        }
        #pragma unroll
        for (int j = 0; j < 4; ++j) {
            const float4 mk = *reinterpret_cast<const float4*>(mb + kv + j * 16 + g * 4);
            s[j][0] -= MASKC * mk.x; s[j][1] -= MASKC * mk.y;
            s[j][2] -= MASKC * mk.z; s[j][3] -= MASKC * mk.w;
        }

        float pm = fmaxf(fmaxf(s[0][0], s[0][1]), fmaxf(s[0][2], s[0][3]));
        #pragma unroll
        for (int j = 1; j < 4; ++j)
            pm = fmaxf(pm, fmaxf(fmaxf(s[j][0], s[j][1]), fmaxf(s[j][2], s[j][3])));
        pm = fmaxf(pm, __shfl_xor(pm, 16));
        pm = fmaxf(pm, __shfl_xor(pm, 32));

        if (__any(pm > m_run)) {          // exact defer-rescale: skip when max unchanged
            const float mnew = fmaxf(m_run, pm);
            const float scl = exp2f(m_run - mnew);
            l_run *= scl;
            #pragma unroll
            for (int r = 0; r < 4; ++r) { o0[r] *= scl; o1[r] *= scl; }
            m_run = mnew;
        }

        float p[16];
        #pragma unroll
        for (int j = 0; j < 4; ++j)
            #pragma unroll
            for (int r = 0; r < 4; ++r)
                p[j * 4 + r] = exp2f(s[j][r] - m_run);

        float ps = 0.f;
        #pragma unroll
        for (int i = 0; i < 16; ++i) ps += p[i];
        ps += __shfl_xor(ps, 16);
        ps += __shfl_xor(ps, 32);
        l_run += ps;

        bf16x8 pf0, pf1;
        #pragma unroll
        for (int i = 0; i < 8; ++i) { pf0[i] = (__bf16)p[i]; pf1[i] = (__bf16)p[8 + i]; }

        bf16x4 a0 = *reinterpret_cast<const bf16x4*>(vrow0 + kv + g * 4);
        bf16x4 a1 = *reinterpret_cast<const bf16x4*>(vrow0 + kv + 16 + g * 4);
        bf16x4 a2 = *reinterpret_cast<const bf16x4*>(vrow0 + kv + 32 + g * 4);
        bf16x4 a3 = *reinterpret_cast<const bf16x4*>(vrow0 + kv + 48 + g * 4);
        bf16x4 c0 = *reinterpret_cast<const bf16x4*>(vrow1 + kv + g * 4);
        bf16x4 c1 = *reinterpret_cast<const bf16x4*>(vrow1 + kv + 16 + g * 4);
        bf16x4 c2 = *reinterpret_cast<const bf16x4*>(vrow1 + kv + 32 + g * 4);
        bf16x4 c3 = *reinterpret_cast<const bf16x4*>(vrow1 + kv + 48 + g * 4);
        bf16x8 vf00 = __builtin_shufflevector(a0, a1, 0, 1, 2, 3, 4, 5, 6, 7);
        bf16x8 vf01 = __builtin_shufflevector(a2, a3, 0, 1, 2, 3, 4, 5, 6, 7);
        bf16x8 vf10 = __builtin_shufflevector(c0, c1, 0, 1, 2, 3, 4, 5, 6, 7);
        bf16x8 vf11 = __builtin_shufflevector(c2, c3, 0, 1, 2, 3, 4, 5, 6, 7);

        o0 = __builtin_amdgcn_mfma_f32_16x16x32_bf16(vf00, pf0, o0, 0, 0, 0);
        o0 = __builtin_amdgcn_mfma_f32_16x16x32_bf16(vf01, pf1, o0, 0, 0, 0);
        o1 = __builtin_amdgcn_mfma_f32_16x16x32_bf16(vf10, pf0, o1, 0, 0, 0);
        o1 = __builtin_amdgcn_mfma_f32_16x16x32_bf16(vf11, pf1, o1, 0, 0, 0);
    }

    // write per-wave partials
    part[w][lane][0] = m_run;
    part[w][lane][1] = l_run;
    #pragma unroll
    for (int r = 0; r < 4; ++r) { part[w][lane][2 + r] = o0[r]; part[w][lane][6 + r] = o1[r]; }
    __syncthreads();

    if (w == 0) {
        float mw[4];
        float mt = -3.0e38f;
        #pragma unroll
        for (int ww = 0; ww < 4; ++ww) { mw[ww] = part[ww][lane][0]; mt = fmaxf(mt, mw[ww]); }
        float lt = 0.f, ot[8] = {};
        #pragma unroll
        for (int ww = 0; ww < 4; ++ww) {
            const float f = exp2f(mw[ww] - mt);
            lt += part[ww][lane][1] * f;
            #pragma unroll
            for (int i = 0; i < 8; ++i) ot[i] += part[ww][lane][2 + i] * f;
        }
        const float inv = 1.f / lt;
        float* cp = ctx + ((size_t)b * NQ + q0 + lr) * DIM + h * HD;
        #pragma unroll
        for (int r = 0; r < 4; ++r) {
            cp[g * 4 + r]      = ot[r] * inv;
            cp[16 + g * 4 + r] = ot[4 + r] * inv;
        }
    }
}

extern "C" void kernel_launch(void* const* d_in, const int* in_sizes, int n_in,
                              void* d_out, int out_size, void* d_ws, size_t ws_size,
                              hipStream_t stream)
{
    const float* Xq   = (const float*)d_in[0];
    const float* Xk   = (const float*)d_in[1];
    const float* Xv   = (const float*)d_in[2];
    const float* mask = (const float*)d_in[3];
    const float* Wq   = (const float*)d_in[4];
    const float* bq   = (const float*)d_in[5];
    const float* Wk   = (const float*)d_in[6];
    const float* bk   = (const float*)d_in[7];
    const float* Wv   = (const float*)d_in[8];
    const float* bv   = (const float*)d_in[9];
    const float* Wo   = (const float*)d_in[10];
    const float* bo   = (const float*)d_in[11];

    char* ws = (char*)d_ws;
    __bf16* qh  = (__bf16*)(ws + OFF_QH);
    __bf16* kh  = (__bf16*)(ws + OFF_KH);
    __bf16* vtp = (__bf16*)(ws + OFF_VT);
    float*  ctx = (float*)(ws + OFF_CTX);
    __bf16* Wb  = (__bf16*)(ws + OFF_W);

    prep_weights_kernel<<<256, 256, 0, stream>>>(Wq, Wk, Wv, Wo, Wb);
    proj_kernel<0><<<BATCH * NQ / 64, 256, 0, stream>>>(Xq, Wb,          bq, QSCALE, qh,  NQ);
    proj_kernel<0><<<BATCH * SEQ / 64, 256, 0, stream>>>(Xk, Wb + 65536,  bk, 1.f,    kh,  SEQ);
    proj_kernel<1><<<BATCH * SEQ / 64, 256, 0, stream>>>(Xv, Wb + 131072, bv, 1.f,    vtp, SEQ);
    attn_kernel<<<1024, 256, 0, stream>>>(qh, kh, vtp, mask, ctx);
    proj_kernel<2><<<BATCH * NQ / 64, 256, 0, stream>>>(ctx, Wb + 196608, bo, 1.f,    d_out, NQ);
}

// Round 3
// 105.477 us; speedup vs baseline: 2.0486x; 2.0486x over previous
//
#include <hip/hip_runtime.h>
#include <hip/hip_bf16.h>

typedef __bf16 bf16x8 __attribute__((ext_vector_type(8)));
typedef __bf16 bf16x4 __attribute__((ext_vector_type(4)));
typedef float  f32x4  __attribute__((ext_vector_type(4)));

constexpr int BATCH = 2, H = 8, NQ = 1024, SEQ = 8192, DIM = 256, HD = 32;
constexpr int CHUNKS = 8, KVCHUNK = SEQ / CHUNKS;   // 8 x 1024
constexpr float SCALE = 0.17677669529663687f;   // 32^-0.5
constexpr float LOG2E = 1.4426950408889634f;
constexpr float QSCALE = SCALE * LOG2E;         // fold log2(e): softmax in exp2 domain
constexpr float MASKC = 100.0f * LOG2E;

// workspace layout (bytes)
constexpr size_t OFF_QH  = 0;                                      // bf16 [B*H][NQ][32]
constexpr size_t OFF_KH  = OFF_QH  + (size_t)BATCH*H*NQ*HD*2;      // bf16 [B*H][S][32]
constexpr size_t OFF_VT  = OFF_KH  + (size_t)BATCH*H*SEQ*HD*2;     // bf16 [B*H][32][S]
constexpr size_t OFF_CTX = OFF_VT  + (size_t)BATCH*H*SEQ*HD*2;     // f32  [B*NQ][256]
constexpr size_t OFF_W   = OFF_CTX + (size_t)BATCH*NQ*DIM*4;       // bf16 4 x [256][256]
constexpr size_t OFF_PML = OFF_W   + (size_t)4*DIM*DIM*2;          // f32x2 [CHUNKS][16][NQ]
constexpr size_t OFF_PO  = OFF_PML + (size_t)CHUNKS*16*NQ*8;       // f32 [CHUNKS][16][NQ][32]

__device__ __forceinline__ float fast_exp2(float x) {
    float r;
    asm("v_exp_f32 %0, %1" : "=v"(r) : "v"(x));
    return r;
}

__global__ void prep_weights_kernel(const float* __restrict__ Wq, const float* __restrict__ Wk,
                                    const float* __restrict__ Wv, const float* __restrict__ Wo,
                                    __bf16* __restrict__ out) {
    int i = blockIdx.x * 256 + threadIdx.x;          // 65536 threads
    out[i]          = (__bf16)(Wq[i] * QSCALE);      // fold q-scale * log2e into Wq
    out[65536 + i]  = (__bf16)(Wk[i]);
    out[131072 + i] = (__bf16)(Wv[i]);
    out[196608 + i] = (__bf16)(Wo[i]);
}

// Y = bf16(X[M x 256]) @ Wbf^T + bias.  Block: 64 rows x all 256 cols, 4 waves.
// MODE 0: bf16 head layout [b*H+h][row][hd]   (Q and K)
// MODE 1: bf16 transposed  [b*H+h][hd][row]   (V^T; MFMA operands swapped)
// MODE 2: f32 plain [m][n]                    (final output)
template<int MODE>
__global__ __launch_bounds__(256, 2)
void proj_kernel(const float* __restrict__ X, const __bf16* __restrict__ W,
                 const float* __restrict__ bias, float bias_scale,
                 void* __restrict__ outp, int Mb)
{
    __shared__ __bf16 Ash[64][40];    // 64 rows x 32 k (+8 pad)
    __shared__ __bf16 Bsh[256][40];   // 256 n  x 32 k (+8 pad)
    const int m0 = blockIdx.x * 64;
    const int t = threadIdx.x;
    const int w = t >> 6;
    const int lane = t & 63;
    const int g = lane >> 4;
    const int lr = lane & 15;

    f32x4 acc[4][4] = {};

    for (int kk = 0; kk < DIM; kk += 32) {
        __syncthreads();
        #pragma unroll
        for (int i = 0; i < 2; ++i) {
            int c = t * 2 + i;
            int row = c >> 3;
            int q = c & 7;
            const float4 v = *reinterpret_cast<const float4*>(X + (size_t)(m0 + row) * DIM + kk + q * 4);
            bf16x4 bv;
            bv[0] = (__bf16)v.x; bv[1] = (__bf16)v.y; bv[2] = (__bf16)v.z; bv[3] = (__bf16)v.w;
            *reinterpret_cast<bf16x4*>(&Ash[row][q * 4]) = bv;
        }
        #pragma unroll
        for (int i = 0; i < 4; ++i) {
            int c = t * 4 + i;
            int n = c >> 2;
            int q = c & 3;
            *reinterpret_cast<bf16x8*>(&Bsh[n][q * 8]) =
                *reinterpret_cast<const bf16x8*>(W + (size_t)n * DIM + kk + q * 8);
        }
        __syncthreads();

        bf16x8 af[4], bfr[4];
        #pragma unroll
        for (int mt = 0; mt < 4; ++mt)
            af[mt] = *reinterpret_cast<const bf16x8*>(&Ash[mt * 16 + lr][g * 8]);
        #pragma unroll
        for (int nt = 0; nt < 4; ++nt)
            bfr[nt] = *reinterpret_cast<const bf16x8*>(&Bsh[w * 64 + nt * 16 + lr][g * 8]);
        #pragma unroll
        for (int mt = 0; mt < 4; ++mt)
            #pragma unroll
            for (int nt = 0; nt < 4; ++nt) {
                if (MODE == 1)
                    acc[mt][nt] = __builtin_amdgcn_mfma_f32_16x16x32_bf16(bfr[nt], af[mt], acc[mt][nt], 0, 0, 0);
                else
                    acc[mt][nt] = __builtin_amdgcn_mfma_f32_16x16x32_bf16(af[mt], bfr[nt], acc[mt][nt], 0, 0, 0);
            }
    }

    const int bb = m0 / Mb;            // whole block lies in one batch (64 | Mb)
    const int sbase = m0 - bb * Mb;

    if (MODE == 0) {
        __bf16* outb = (__bf16*)outp;
        #pragma unroll
        for (int nt = 0; nt < 4; ++nt) {
            int n = w * 64 + nt * 16 + lr;
            float bv = bias[n] * bias_scale;
            int h = n >> 5, hd = n & 31;
            __bf16* op = outb + ((size_t)(bb * H + h) * Mb) * 32 + hd;
            #pragma unroll
            for (int mt = 0; mt < 4; ++mt)
                #pragma unroll
                for (int r = 0; r < 4; ++r) {
                    int s = sbase + mt * 16 + g * 4 + r;
                    op[(size_t)s * 32] = (__bf16)(acc[mt][nt][r] + bv);
                }
        }
    } else if (MODE == 1) {
        __bf16* outb = (__bf16*)outp;
        #pragma unroll
        for (int nt = 0; nt < 4; ++nt)
            #pragma unroll
            for (int r = 0; r < 4; ++r) {
                int n = w * 64 + nt * 16 + g * 4 + r;   // D rows = n (operands swapped)
                float bv = bias[n] * bias_scale;
                int h = n >> 5, hd = n & 31;
                __bf16* op = outb + ((size_t)(bb * H + h) * 32 + hd) * SEQ;
                #pragma unroll
                for (int mt = 0; mt < 4; ++mt) {
                    int s = sbase + mt * 16 + lr;       // D cols = m (contiguous per 16 lanes)
                    op[s] = (__bf16)(acc[mt][nt][r] + bv);
                }
            }
    } else {
        float* outf = (float*)outp;
        #pragma unroll
        for (int nt = 0; nt < 4; ++nt) {
            int n = w * 64 + nt * 16 + lr;
            float bv = bias[n] * bias_scale;
            #pragma unroll
            for (int mt = 0; mt < 4; ++mt)
                #pragma unroll
                for (int r = 0; r < 4; ++r) {
                    int m = m0 + mt * 16 + g * 4 + r;
                    outf[(size_t)m * DIM + n] = acc[mt][nt][r] + bv;
                }
        }
    }
}

// Flash attention with LDS-shared K/V tiles + split-K across blocks.
// Grid 1024 = 16 bh (low bits -> XCD locality) x 8 q-tiles(128 rows) x 8 kv-chunks(1024).
// Block = 4 waves; wave w owns q-rows [qt*128 + w*32, +32) as 2 MFMA fragments.
// Per 64-kv step: K-tile(64x32) and V^T-tile(32x64) staged in LDS, shared by all waves.
// Unnormalized partials (m, l, o[32]) per q-row per chunk -> Pml/Po; combine_kernel merges.
__global__ __launch_bounds__(256, 4)
void attn_kernel(const __bf16* __restrict__ qh, const __bf16* __restrict__ kh,
                 const __bf16* __restrict__ vt, const float* __restrict__ mask,
                 float2* __restrict__ Pml, float* __restrict__ Po)
{
    __shared__ __bf16 Ksh[64][40];    // kv-rows x 32 hd (+8 pad)
    __shared__ __bf16 Vsh[32][72];    // hd-rows x 64 kv (+8 pad)

    const int bid = blockIdx.x;
    const int bh = bid & 15;
    const int qt = (bid >> 4) & 7;
    const int ck = bid >> 7;                 // 0..7
    const int b = bh >> 3;
    const int t = threadIdx.x;
    const int w = t >> 6, lane = t & 63, g = lane >> 4, lr = lane & 15;
    const int q0 = qt * 128 + w * 32;

    bf16x8 qf[2];
    #pragma unroll
    for (int qi = 0; qi < 2; ++qi)
        qf[qi] = *reinterpret_cast<const bf16x8*>(qh + ((size_t)bh * NQ + q0 + qi * 16 + lr) * HD + g * 8);

    const __bf16* kb = kh + (size_t)bh * SEQ * HD;
    const __bf16* vb = vt + (size_t)bh * HD * SEQ;
    const float* mb = mask + (size_t)b * SEQ;

    // staging indices (all 256 threads)
    const int kr = t >> 2, kc = (t & 3) * 8;     // K: 64 rows x 4x16B
    const int vr = t >> 3, vc = (t & 7) * 8;     // V: 32 rows x 8x16B

    const int kv0 = ck * KVCHUNK;
    float m_run[2] = {-3.0e38f, -3.0e38f}, l_run[2] = {0.f, 0.f};
    f32x4 o[2][2] = {};
    const f32x4 zero = {0.f, 0.f, 0.f, 0.f};

    for (int kv = kv0; kv < kv0 + KVCHUNK; kv += 64) {
        __syncthreads();
        *reinterpret_cast<bf16x8*>(&Ksh[kr][kc]) =
            *reinterpret_cast<const bf16x8*>(kb + (size_t)(kv + kr) * HD + kc);
        *reinterpret_cast<bf16x8*>(&Vsh[vr][vc]) =
            *reinterpret_cast<const bf16x8*>(vb + (size_t)vr * SEQ + kv + vc);
        __syncthreads();

        // shared fragments for this tile
        bf16x8 kf[4];
        #pragma unroll
        for (int j = 0; j < 4; ++j)
            kf[j] = *reinterpret_cast<const bf16x8*>(&Ksh[j * 16 + lr][g * 8]);

        bf16x4 vraw[2][4];
        #pragma unroll
        for (int hf = 0; hf < 2; ++hf)
            #pragma unroll
            for (int j = 0; j < 4; ++j)
                vraw[hf][j] = *reinterpret_cast<const bf16x4*>(&Vsh[hf * 16 + lr][j * 16 + g * 4]);
        bf16x8 vf[2][2];
        #pragma unroll
        for (int hf = 0; hf < 2; ++hf) {
            vf[hf][0] = __builtin_shufflevector(vraw[hf][0], vraw[hf][1], 0, 1, 2, 3, 4, 5, 6, 7);
            vf[hf][1] = __builtin_shufflevector(vraw[hf][2], vraw[hf][3], 0, 1, 2, 3, 4, 5, 6, 7);
        }

        float4 mk[4];
        #pragma unroll
        for (int j = 0; j < 4; ++j)
            mk[j] = *reinterpret_cast<const float4*>(mb + kv + j * 16 + g * 4);

        #pragma unroll
        for (int qi = 0; qi < 2; ++qi) {
            f32x4 s[4];
            #pragma unroll
            for (int j = 0; j < 4; ++j)
                s[j] = __builtin_amdgcn_mfma_f32_16x16x32_bf16(kf[j], qf[qi], zero, 0, 0, 0);
            #pragma unroll
            for (int j = 0; j < 4; ++j) {
                s[j][0] = __builtin_fmaf(-MASKC, mk[j].x, s[j][0]);
                s[j][1] = __builtin_fmaf(-MASKC, mk[j].y, s[j][1]);
                s[j][2] = __builtin_fmaf(-MASKC, mk[j].z, s[j][2]);
                s[j][3] = __builtin_fmaf(-MASKC, mk[j].w, s[j][3]);
            }

            float pm = fmaxf(fmaxf(s[0][0], s[0][1]), fmaxf(s[0][2], s[0][3]));
            #pragma unroll
            for (int j = 1; j < 4; ++j)
                pm = fmaxf(pm, fmaxf(fmaxf(s[j][0], s[j][1]), fmaxf(s[j][2], s[j][3])));
            pm = fmaxf(pm, __shfl_xor(pm, 16));
            pm = fmaxf(pm, __shfl_xor(pm, 32));

            if (__any(pm > m_run[qi])) {      // exact defer-rescale
                const float mnew = fmaxf(m_run[qi], pm);
                const float scl = fast_exp2(m_run[qi] - mnew);
                l_run[qi] *= scl;
                #pragma unroll
                for (int r = 0; r < 4; ++r) { o[qi][0][r] *= scl; o[qi][1][r] *= scl; }
                m_run[qi] = mnew;
            }

            float p[16];
            #pragma unroll
            for (int j = 0; j < 4; ++j)
                #pragma unroll
                for (int r = 0; r < 4; ++r)
                    p[j * 4 + r] = fast_exp2(s[j][r] - m_run[qi]);

            float ps = 0.f;
            #pragma unroll
            for (int i = 0; i < 16; ++i) ps += p[i];
            ps += __shfl_xor(ps, 16);
            ps += __shfl_xor(ps, 32);
            l_run[qi] += ps;

            bf16x8 pf0, pf1;
            #pragma unroll
            for (int i = 0; i < 8; ++i) { pf0[i] = (__bf16)p[i]; pf1[i] = (__bf16)p[8 + i]; }

            o[qi][0] = __builtin_amdgcn_mfma_f32_16x16x32_bf16(vf[0][0], pf0, o[qi][0], 0, 0, 0);
            o[qi][0] = __builtin_amdgcn_mfma_f32_16x16x32_bf16(vf[0][1], pf1, o[qi][0], 0, 0, 0);
            o[qi][1] = __builtin_amdgcn_mfma_f32_16x16x32_bf16(vf[1][0], pf0, o[qi][1], 0, 0, 0);
            o[qi][1] = __builtin_amdgcn_mfma_f32_16x16x32_bf16(vf[1][1], pf1, o[qi][1], 0, 0, 0);
        }
    }

    // write unnormalized partials
    #pragma unroll
    for (int qi = 0; qi < 2; ++qi) {
        const int row = q0 + qi * 16 + lr;
        const size_t base = ((size_t)ck * 16 + bh) * NQ + row;
        if (g == 0) Pml[base] = make_float2(m_run[qi], l_run[qi]);
        #pragma unroll
        for (int hf = 0; hf < 2; ++hf)
            *reinterpret_cast<f32x4*>(Po + base * 32 + hf * 16 + g * 4) = o[qi][hf];
    }
}

// Merge split-K partials: ctx[b][row][h*32+hd] = sum_c o_c * 2^(m_c-mt) / sum_c l_c * 2^(m_c-mt)
__global__ __launch_bounds__(256)
void combine_kernel(const float2* __restrict__ Pml, const float* __restrict__ Po,
                    float* __restrict__ ctx)
{
    const int idx = blockIdx.x * 256 + threadIdx.x;   // 16*1024*32
    const int hd = idx & 31;
    const int row = (idx >> 5) & (NQ - 1);
    const int bh = idx >> 15;
    const int b = bh >> 3, h = bh & 7;

    float2 ml[CHUNKS];
    float mt = -3.0e38f;
    #pragma unroll
    for (int c = 0; c < CHUNKS; ++c) {
        ml[c] = Pml[((size_t)c * 16 + bh) * NQ + row];
        mt = fmaxf(mt, ml[c].x);
    }
    float lsum = 0.f, osum = 0.f;
    #pragma unroll
    for (int c = 0; c < CHUNKS; ++c) {
        const float f = fast_exp2(ml[c].x - mt);
        lsum += ml[c].y * f;
        osum += Po[(((size_t)c * 16 + bh) * NQ + row) * 32 + hd] * f;
    }
    ctx[((size_t)b * NQ + row) * DIM + h * HD + hd] = osum / lsum;
}

extern "C" void kernel_launch(void* const* d_in, const int* in_sizes, int n_in,
                              void* d_out, int out_size, void* d_ws, size_t ws_size,
                              hipStream_t stream)
{
    const float* Xq   = (const float*)d_in[0];
    const float* Xk   = (const float*)d_in[1];
    const float* Xv   = (const float*)d_in[2];
    const float* mask = (const float*)d_in[3];
    const float* Wq   = (const float*)d_in[4];
    const float* bq   = (const float*)d_in[5];
    const float* Wk   = (const float*)d_in[6];
    const float* bk   = (const float*)d_in[7];
    const float* Wv   = (const float*)d_in[8];
    const float* bv   = (const float*)d_in[9];
    const float* Wo   = (const float*)d_in[10];
    const float* bo   = (const float*)d_in[11];

    char* ws = (char*)d_ws;
    __bf16* qh  = (__bf16*)(ws + OFF_QH);
    __bf16* kh  = (__bf16*)(ws + OFF_KH);
    __bf16* vtp = (__bf16*)(ws + OFF_VT);
    float*  ctx = (float*)(ws + OFF_CTX);
    __bf16* Wb  = (__bf16*)(ws + OFF_W);
    float2* Pml = (float2*)(ws + OFF_PML);
    float*  Po  = (float*)(ws + OFF_PO);

    prep_weights_kernel<<<256, 256, 0, stream>>>(Wq, Wk, Wv, Wo, Wb);
    proj_kernel<0><<<BATCH * NQ / 64, 256, 0, stream>>>(Xq, Wb,          bq, QSCALE, qh,  NQ);
    proj_kernel<0><<<BATCH * SEQ / 64, 256, 0, stream>>>(Xk, Wb + 65536,  bk, 1.f,    kh,  SEQ);
    proj_kernel<1><<<BATCH * SEQ / 64, 256, 0, stream>>>(Xv, Wb + 131072, bv, 1.f,    vtp, SEQ);
    attn_kernel<<<16 * 8 * CHUNKS, 256, 0, stream>>>(qh, kh, vtp, mask, Pml, Po);
    combine_kernel<<<16 * NQ * 32 / 256, 256, 0, stream>>>(Pml, Po, ctx);
    proj_kernel<2><<<BATCH * NQ / 64, 256, 0, stream>>>(ctx, Wb + 196608, bo, 1.f,    d_out, NQ);
}

// Round 6
// 97.625 us; speedup vs baseline: 2.2134x; 1.0804x over previous
//
#include <hip/hip_runtime.h>
#include <hip/hip_bf16.h>

typedef __bf16 bf16x8 __attribute__((ext_vector_type(8)));
typedef __bf16 bf16x4 __attribute__((ext_vector_type(4)));
typedef float  f32x4  __attribute__((ext_vector_type(4)));

constexpr int BATCH = 2, H = 8, NQ = 1024, SEQ = 8192, DIM = 256, HD = 32;
constexpr int CHUNKS = 8, KVCHUNK = SEQ / CHUNKS;   // 8 x 1024
constexpr float SCALE = 0.17677669529663687f;   // 32^-0.5
constexpr float LOG2E = 1.4426950408889634f;
constexpr float QSCALE = SCALE * LOG2E;         // fold log2(e): softmax in exp2 domain
constexpr float MASKC = 100.0f * LOG2E;

// workspace layout (bytes) — round-3 layout
constexpr size_t OFF_QH  = 0;                                      // bf16 [B*H][NQ][32]
constexpr size_t OFF_KH  = OFF_QH  + (size_t)BATCH*H*NQ*HD*2;      // bf16 [B*H][S][32]
constexpr size_t OFF_VT  = OFF_KH  + (size_t)BATCH*H*SEQ*HD*2;     // bf16 [B*H][32][S]
constexpr size_t OFF_CTX = OFF_VT  + (size_t)BATCH*H*SEQ*HD*2;     // f32  [B*NQ][256]
constexpr size_t OFF_W   = OFF_CTX + (size_t)BATCH*NQ*DIM*4;       // bf16 4 x [256][256]
constexpr size_t OFF_PML = OFF_W   + (size_t)4*DIM*DIM*2;          // f32x2 [CHUNKS][16][NQ]
constexpr size_t OFF_PO  = OFF_PML + (size_t)CHUNKS*16*NQ*8;       // f32 [CHUNKS][16][NQ][32]

__device__ __forceinline__ float fast_exp2(float x) {
    float r;
    asm("v_exp_f32 %0, %1" : "=v"(r) : "v"(x));
    return r;
}

__global__ void prep_weights_kernel(const float* __restrict__ Wq, const float* __restrict__ Wk,
                                    const float* __restrict__ Wv, const float* __restrict__ Wo,
                                    __bf16* __restrict__ out) {
    int i = blockIdx.x * 256 + threadIdx.x;          // 65536 threads
    out[i]          = (__bf16)(Wq[i] * QSCALE);      // fold q-scale * log2e into Wq
    out[65536 + i]  = (__bf16)(Wk[i]);
    out[131072 + i] = (__bf16)(Wv[i]);
    out[196608 + i] = (__bf16)(Wo[i]);
}

// Y = bf16(X[M x 256]) @ Wbf^T + bias.  Tile 128 rows x 128 cols, BK=64, 4 waves (64x64 each).
// grid = (M/128) * 2;  m0 = (bid>>1)*128, n0 = (bid&1)*128.
// MODE 0: bf16 head layout [b*H+h][row][hd]   (Q and K)
// MODE 1: bf16 transposed  [b*H+h][hd][row]   (V^T; MFMA operands swapped)
// MODE 2: f32 plain [m][n]                    (final output)
template<int MODE>
__global__ __launch_bounds__(256, 2)
void proj_kernel(const float* __restrict__ X, const __bf16* __restrict__ W,
                 const float* __restrict__ bias, float bias_scale,
                 void* __restrict__ outp, int Mb)
{
    __shared__ __bf16 Ash[128][72];   // 128 rows x 64 k (+8 pad; stride 144B = 9x16 aligned)
    __shared__ __bf16 Bsh[128][72];   // 128 n   x 64 k (+8 pad)
    const int m0 = (blockIdx.x >> 1) * 128;
    const int n0 = (blockIdx.x & 1) * 128;
    const int t = threadIdx.x;
    const int w = t >> 6;
    const int lane = t & 63;
    const int g = lane >> 4;
    const int lr = lane & 15;
    const int wr = w >> 1, wc = w & 1;

    f32x4 acc[4][4] = {};

    for (int kk = 0; kk < DIM; kk += 64) {
        __syncthreads();
        // stage A: 128x64 fp32 -> bf16 (2048 float4 chunks)
        #pragma unroll
        for (int i = 0; i < 8; ++i) {
            int c = i * 256 + t;
            int row = c >> 4;
            int q = c & 15;
            const float4 v = *reinterpret_cast<const float4*>(X + (size_t)(m0 + row) * DIM + kk + q * 4);
            bf16x4 bv;
            bv[0] = (__bf16)v.x; bv[1] = (__bf16)v.y; bv[2] = (__bf16)v.z; bv[3] = (__bf16)v.w;
            *reinterpret_cast<bf16x4*>(&Ash[row][q * 4]) = bv;
        }
        // stage B: 128x64 bf16 (1024 8-elem chunks)
        #pragma unroll
        for (int i = 0; i < 4; ++i) {
            int c = i * 256 + t;
            int row = c >> 3;
            int q = c & 7;
            *reinterpret_cast<bf16x8*>(&Bsh[row][q * 8]) =
                *reinterpret_cast<const bf16x8*>(W + (size_t)(n0 + row) * DIM + kk + q * 8);
        }
        __syncthreads();

        #pragma unroll
        for (int ks = 0; ks < 2; ++ks) {
            bf16x8 af[4], bfr[4];
            #pragma unroll
            for (int mt = 0; mt < 4; ++mt)
                af[mt] = *reinterpret_cast<const bf16x8*>(&Ash[wr * 64 + mt * 16 + lr][ks * 32 + g * 8]);
            #pragma unroll
            for (int nt = 0; nt < 4; ++nt)
                bfr[nt] = *reinterpret_cast<const bf16x8*>(&Bsh[wc * 64 + nt * 16 + lr][ks * 32 + g * 8]);
            #pragma unroll
            for (int mt = 0; mt < 4; ++mt)
                #pragma unroll
                for (int nt = 0; nt < 4; ++nt) {
                    if (MODE == 1)
                        acc[mt][nt] = __builtin_amdgcn_mfma_f32_16x16x32_bf16(bfr[nt], af[mt], acc[mt][nt], 0, 0, 0);
                    else
                        acc[mt][nt] = __builtin_amdgcn_mfma_f32_16x16x32_bf16(af[mt], bfr[nt], acc[mt][nt], 0, 0, 0);
                }
        }
    }

    const int bb = m0 / Mb;            // whole tile lies in one batch (128 | Mb)
    const int sbase = m0 - bb * Mb + wr * 64;

    if (MODE == 0) {
        __bf16* outb = (__bf16*)outp;
        #pragma unroll
        for (int nt = 0; nt < 4; ++nt) {
            int n = n0 + wc * 64 + nt * 16 + lr;
            float bv = bias[n] * bias_scale;
            int h = n >> 5, hd = n & 31;
            __bf16* op = outb + ((size_t)(bb * H + h) * Mb) * 32 + hd;
            #pragma unroll
            for (int mt = 0; mt < 4; ++mt)
                #pragma unroll
                for (int r = 0; r < 4; ++r) {
                    int s = sbase + mt * 16 + g * 4 + r;
                    op[(size_t)s * 32] = (__bf16)(acc[mt][nt][r] + bv);
                }
        }
    } else if (MODE == 1) {
        __bf16* outb = (__bf16*)outp;
        #pragma unroll
        for (int nt = 0; nt < 4; ++nt)
            #pragma unroll
            for (int r = 0; r < 4; ++r) {
                int n = n0 + wc * 64 + nt * 16 + g * 4 + r;   // D rows = n (operands swapped)
                float bv = bias[n] * bias_scale;
                int h = n >> 5, hd = n & 31;
                __bf16* op = outb + ((size_t)(bb * H + h) * 32 + hd) * SEQ;
                #pragma unroll
                for (int mt = 0; mt < 4; ++mt) {
                    int s = sbase + mt * 16 + lr;             // D cols = m (contiguous per 16 lanes)
                    op[s] = (__bf16)(acc[mt][nt][r] + bv);
                }
            }
    } else {
        float* outf = (float*)outp;
        #pragma unroll
        for (int nt = 0; nt < 4; ++nt) {
            int n = n0 + wc * 64 + nt * 16 + lr;
            float bv = bias[n] * bias_scale;
            #pragma unroll
            for (int mt = 0; mt < 4; ++mt)
                #pragma unroll
                for (int r = 0; r < 4; ++r) {
                    int m = m0 + wr * 64 + mt * 16 + g * 4 + r;
                    outf[(size_t)m * DIM + n] = acc[mt][nt][r] + bv;
                }
        }
    }
}

// Flash attention with LDS-shared K/V tiles + split-K across blocks (round-3 proven version).
// Grid 1024 = 16 bh (low bits -> XCD locality) x 8 q-tiles(128 rows) x 8 kv-chunks(1024).
// Block = 4 waves; wave w owns q-rows [qt*128 + w*32, +32) as 2 MFMA fragments.
// Per 64-kv step: K-tile(64x32) and V^T-tile(32x64) staged in LDS, shared by all waves.
// Unnormalized partials (m, l, o[32]) per q-row per chunk -> Pml/Po; combine_kernel merges.
__global__ __launch_bounds__(256, 4)
void attn_kernel(const __bf16* __restrict__ qh, const __bf16* __restrict__ kh,
                 const __bf16* __restrict__ vt, const float* __restrict__ mask,
                 float2* __restrict__ Pml, float* __restrict__ Po)
{
    __shared__ __bf16 Ksh[64][40];    // kv-rows x 32 hd (+8 pad)
    __shared__ __bf16 Vsh[32][72];    // hd-rows x 64 kv (+8 pad)

    const int bid = blockIdx.x;
    const int bh = bid & 15;
    const int qt = (bid >> 4) & 7;
    const int ck = bid >> 7;                 // 0..7
    const int b = bh >> 3;
    const int t = threadIdx.x;
    const int w = t >> 6, lane = t & 63, g = lane >> 4, lr = lane & 15;
    const int q0 = qt * 128 + w * 32;

    bf16x8 qf[2];
    #pragma unroll
    for (int qi = 0; qi < 2; ++qi)
        qf[qi] = *reinterpret_cast<const bf16x8*>(qh + ((size_t)bh * NQ + q0 + qi * 16 + lr) * HD + g * 8);

    const __bf16* kb = kh + (size_t)bh * SEQ * HD;
    const __bf16* vb = vt + (size_t)bh * HD * SEQ;
    const float* mb = mask + (size_t)b * SEQ;

    // staging indices (all 256 threads)
    const int kr = t >> 2, kc = (t & 3) * 8;     // K: 64 rows x 4x16B
    const int vr = t >> 3, vc = (t & 7) * 8;     // V: 32 rows x 8x16B

    const int kv0 = ck * KVCHUNK;
    float m_run[2] = {-3.0e38f, -3.0e38f}, l_run[2] = {0.f, 0.f};
    f32x4 o[2][2] = {};
    const f32x4 zero = {0.f, 0.f, 0.f, 0.f};

    for (int kv = kv0; kv < kv0 + KVCHUNK; kv += 64) {
        __syncthreads();
        *reinterpret_cast<bf16x8*>(&Ksh[kr][kc]) =
            *reinterpret_cast<const bf16x8*>(kb + (size_t)(kv + kr) * HD + kc);
        *reinterpret_cast<bf16x8*>(&Vsh[vr][vc]) =
            *reinterpret_cast<const bf16x8*>(vb + (size_t)vr * SEQ + kv + vc);
        __syncthreads();

        // shared fragments for this tile
        bf16x8 kf[4];
        #pragma unroll
        for (int j = 0; j < 4; ++j)
            kf[j] = *reinterpret_cast<const bf16x8*>(&Ksh[j * 16 + lr][g * 8]);

        bf16x4 vraw[2][4];
        #pragma unroll
        for (int hf = 0; hf < 2; ++hf)
            #pragma unroll
            for (int j = 0; j < 4; ++j)
                vraw[hf][j] = *reinterpret_cast<const bf16x4*>(&Vsh[hf * 16 + lr][j * 16 + g * 4]);
        bf16x8 vf[2][2];
        #pragma unroll
        for (int hf = 0; hf < 2; ++hf) {
            vf[hf][0] = __builtin_shufflevector(vraw[hf][0], vraw[hf][1], 0, 1, 2, 3, 4, 5, 6, 7);
            vf[hf][1] = __builtin_shufflevector(vraw[hf][2], vraw[hf][3], 0, 1, 2, 3, 4, 5, 6, 7);
        }

        float4 mk[4];
        #pragma unroll
        for (int j = 0; j < 4; ++j)
            mk[j] = *reinterpret_cast<const float4*>(mb + kv + j * 16 + g * 4);

        #pragma unroll
        for (int qi = 0; qi < 2; ++qi) {
            f32x4 s[4];
            #pragma unroll
            for (int j = 0; j < 4; ++j)
                s[j] = __builtin_amdgcn_mfma_f32_16x16x32_bf16(kf[j], qf[qi], zero, 0, 0, 0);
            #pragma unroll
            for (int j = 0; j < 4; ++j) {
                s[j][0] = __builtin_fmaf(-MASKC, mk[j].x, s[j][0]);
                s[j][1] = __builtin_fmaf(-MASKC, mk[j].y, s[j][1]);
                s[j][2] = __builtin_fmaf(-MASKC, mk[j].z, s[j][2]);
                s[j][3] = __builtin_fmaf(-MASKC, mk[j].w, s[j][3]);
            }

            float pm = fmaxf(fmaxf(s[0][0], s[0][1]), fmaxf(s[0][2], s[0][3]));
            #pragma unroll
            for (int j = 1; j < 4; ++j)
                pm = fmaxf(pm, fmaxf(fmaxf(s[j][0], s[j][1]), fmaxf(s[j][2], s[j][3])));
            pm = fmaxf(pm, __shfl_xor(pm, 16));
            pm = fmaxf(pm, __shfl_xor(pm, 32));

            if (__any(pm > m_run[qi])) {      // exact defer-rescale
                const float mnew = fmaxf(m_run[qi], pm);
                const float scl = fast_exp2(m_run[qi] - mnew);
                l_run[qi] *= scl;
                #pragma unroll
                for (int r = 0; r < 4; ++r) { o[qi][0][r] *= scl; o[qi][1][r] *= scl; }
                m_run[qi] = mnew;
            }

            float p[16];
            #pragma unroll
            for (int j = 0; j < 4; ++j)
                #pragma unroll
                for (int r = 0; r < 4; ++r)
                    p[j * 4 + r] = fast_exp2(s[j][r] - m_run[qi]);

            float ps = 0.f;
            #pragma unroll
            for (int i = 0; i < 16; ++i) ps += p[i];
            ps += __shfl_xor(ps, 16);
            ps += __shfl_xor(ps, 32);
            l_run[qi] += ps;

            bf16x8 pf0, pf1;
            #pragma unroll
            for (int i = 0; i < 8; ++i) { pf0[i] = (__bf16)p[i]; pf1[i] = (__bf16)p[8 + i]; }

            o[qi][0] = __builtin_amdgcn_mfma_f32_16x16x32_bf16(vf[0][0], pf0, o[qi][0], 0, 0, 0);
            o[qi][0] = __builtin_amdgcn_mfma_f32_16x16x32_bf16(vf[0][1], pf1, o[qi][0], 0, 0, 0);
            o[qi][1] = __builtin_amdgcn_mfma_f32_16x16x32_bf16(vf[1][0], pf0, o[qi][1], 0, 0, 0);
            o[qi][1] = __builtin_amdgcn_mfma_f32_16x16x32_bf16(vf[1][1], pf1, o[qi][1], 0, 0, 0);
        }
    }

    // write unnormalized partials
    #pragma unroll
    for (int qi = 0; qi < 2; ++qi) {
        const int row = q0 + qi * 16 + lr;
        const size_t base = ((size_t)ck * 16 + bh) * NQ + row;
        if (g == 0) Pml[base] = make_float2(m_run[qi], l_run[qi]);
        #pragma unroll
        for (int hf = 0; hf < 2; ++hf)
            *reinterpret_cast<f32x4*>(Po + base * 32 + hf * 16 + g * 4) = o[qi][hf];
    }
}

// Merge split-K partials: ctx[b][row][h*32+hd] = sum_c o_c * 2^(m_c-mt) / sum_c l_c * 2^(m_c-mt)
__global__ __launch_bounds__(256)
void combine_kernel(const float2* __restrict__ Pml, const float* __restrict__ Po,
                    float* __restrict__ ctx)
{
    const int idx = blockIdx.x * 256 + threadIdx.x;   // 16*1024*32
    const int hd = idx & 31;
    const int row = (idx >> 5) & (NQ - 1);
    const int bh = idx >> 15;
    const int b = bh >> 3, h = bh & 7;

    float2 ml[CHUNKS];
    float mt = -3.0e38f;
    #pragma unroll
    for (int c = 0; c < CHUNKS; ++c) {
        ml[c] = Pml[((size_t)c * 16 + bh) * NQ + row];
        mt = fmaxf(mt, ml[c].x);
    }
    float lsum = 0.f, osum = 0.f;
    #pragma unroll
    for (int c = 0; c < CHUNKS; ++c) {
        const float f = fast_exp2(ml[c].x - mt);
        lsum += ml[c].y * f;
        osum += Po[(((size_t)c * 16 + bh) * NQ + row) * 32 + hd] * f;
    }
    ctx[((size_t)b * NQ + row) * DIM + h * HD + hd] = osum / lsum;
}

extern "C" void kernel_launch(void* const* d_in, const int* in_sizes, int n_in,
                              void* d_out, int out_size, void* d_ws, size_t ws_size,
                              hipStream_t stream)
{
    const float* Xq   = (const float*)d_in[0];
    const float* Xk   = (const float*)d_in[1];
    const float* Xv   = (const float*)d_in[2];
    const float* mask = (const float*)d_in[3];
    const float* Wq   = (const float*)d_in[4];
    const float* bq   = (const float*)d_in[5];
    const float* Wk   = (const float*)d_in[6];
    const float* bk   = (const float*)d_in[7];
    const float* Wv   = (const float*)d_in[8];
    const float* bv   = (const float*)d_in[9];
    const float* Wo   = (const float*)d_in[10];
    const float* bo   = (const float*)d_in[11];

    char* ws = (char*)d_ws;
    __bf16* qh  = (__bf16*)(ws + OFF_QH);
    __bf16* kh  = (__bf16*)(ws + OFF_KH);
    __bf16* vtp = (__bf16*)(ws + OFF_VT);
    float*  ctx = (float*)(ws + OFF_CTX);
    __bf16* Wb  = (__bf16*)(ws + OFF_W);
    float2* Pml = (float2*)(ws + OFF_PML);
    float*  Po  = (float*)(ws + OFF_PO);

    prep_weights_kernel<<<256, 256, 0, stream>>>(Wq, Wk, Wv, Wo, Wb);
    proj_kernel<0><<<(BATCH * NQ / 128) * 2, 256, 0, stream>>>(Xq, Wb,          bq, QSCALE, qh,  NQ);
    proj_kernel<0><<<(BATCH * SEQ / 128) * 2, 256, 0, stream>>>(Xk, Wb + 65536,  bk, 1.f,    kh,  SEQ);
    proj_kernel<1><<<(BATCH * SEQ / 128) * 2, 256, 0, stream>>>(Xv, Wb + 131072, bv, 1.f,    vtp, SEQ);
    attn_kernel<<<16 * 8 * CHUNKS, 256, 0, stream>>>(qh, kh, vtp, mask, Pml, Po);
    combine_kernel<<<16 * NQ * 32 / 256, 256, 0, stream>>>(Pml, Po, ctx);
    proj_kernel<2><<<(BATCH * NQ / 128) * 2, 256, 0, stream>>>(ctx, Wb + 196608, bo, 1.f,    d_out, NQ);
}